// Round 1
// baseline (406.802 us; speedup 1.0000x reference)
//
#include <hip/hip_runtime.h>
#include <hip/hip_bf16.h>
#include <cstddef>

#define BB 1024
#define TT 4096
#define LL 30
#define HH 32
// P = 2, DT = 1.0

// ---- fast branch-free tanh: abs error ~1e-7, correct saturation at +/-1 ----
__device__ __forceinline__ float tanh_fast(float x) {
    // tanh(x) = 1 - 2/(exp(2x)+1); exp(2x) = exp2(x * 2*log2(e))
    float t = __builtin_amdgcn_exp2f(x * 2.8853900817779268f);
    float r = __builtin_amdgcn_rcpf(t + 1.0f);
    return fmaf(-2.0f, r, 1.0f);
}

// ---- DPP add step (full-rate VALU cross-lane, no LDS) ----
template <int CTRL>
__device__ __forceinline__ float dpp_add_f(float x) {
    int xi = __float_as_int(x);
    int yi = __builtin_amdgcn_update_dpp(0, xi, CTRL, 0xF, 0xF, true);
    return x + __int_as_float(yi);
}

// sum across each row of 16 lanes; every lane ends with the (bitwise-identical) sum
__device__ __forceinline__ float red16(float x) {
    x = dpp_add_f<0xB1>(x);   // quad_perm [1,0,3,2]  (xor 1)
    x = dpp_add_f<0x4E>(x);   // quad_perm [2,3,0,1]  (xor 2)
    x = dpp_add_f<0x141>(x);  // row_half_mirror      (combine quads within 8)
    x = dpp_add_f<0x140>(x);  // row_mirror           (combine 8-groups within 16)
    return x;
}

// Kernel 1: encoder + sequential Euler scan. 16 lanes per batch chain,
// 4 chains per wave, 256 waves total (1 per CU). Writes z -> out2 (B,T,2).
__global__ __launch_bounds__(64) void ode_scan_kernel(
    const float* __restrict__ x,
    const float* __restrict__ ew1, const float* __restrict__ eb1,
    const float* __restrict__ ew2, const float* __restrict__ eb2,
    const float* __restrict__ fw1, const float* __restrict__ fb1,
    const float* __restrict__ fw2, const float* __restrict__ fb2,
    float* __restrict__ zout)
{
    const int tid = threadIdx.x;
    const int g   = tid & 15;                    // lane within 16-lane group
    const int b   = blockIdx.x * 4 + (tid >> 4); // batch chain
    const int j0  = g;                           // hidden unit A
    const int j1  = g + 16;                      // hidden unit B

    // ---------------- encoder: z0 = tanh(x[:, :30] @ ew1 + eb1) @ ew2 + eb2
    float s0 = eb1[j0], s1 = eb1[j1];
    const float* xb = x + (size_t)b * TT;
    #pragma unroll
    for (int l = 0; l < LL; ++l) {
        float xv = xb[l];  // same address across the 16-lane group -> cache broadcast
        s0 = fmaf(xv, ew1[l * HH + j0], s0);
        s1 = fmaf(xv, ew1[l * HH + j1], s1);
    }
    {
        float h0 = tanh_fast(s0), h1 = tanh_fast(s1);
        float p0 = fmaf(h1, ew2[j1 * 2 + 0], h0 * ew2[j0 * 2 + 0]);
        float p1 = fmaf(h1, ew2[j1 * 2 + 1], h0 * ew2[j0 * 2 + 1]);
        p0 = red16(p0);
        p1 = red16(p1);
        s0 = p0 + eb2[0];
        s1 = p1 + eb2[1];
    }
    float z1 = s0, z2 = s1;

    // ---------------- load f-MLP weights into registers (12 scalars/lane)
    const float w10  = fw1[j0],          w10b = fw1[HH + j0];
    const float w11  = fw1[j1],          w11b = fw1[HH + j1];
    const float b10  = fb1[j0],          b11  = fb1[j1];
    const float w200 = fw2[j0 * 2 + 0],  w201 = fw2[j0 * 2 + 1];
    const float w210 = fw2[j1 * 2 + 0],  w211 = fw2[j1 * 2 + 1];
    const float b20  = fb2[0],           b21  = fb2[1];

    float* zb = zout + (size_t)b * TT * 2;
    if (g == 0) { float2 v; v.x = z1; v.y = z2; *(float2*)zb = v; }

    // ---------------- sequential Euler scan (latency-bound critical path)
    for (int t = 1; t < TT; ++t) {
        float a0 = fmaf(z2, w10b, fmaf(z1, w10, b10));
        float a1 = fmaf(z2, w11b, fmaf(z1, w11, b11));
        float h0 = tanh_fast(a0);
        float h1 = tanh_fast(a1);
        float q0 = fmaf(h1, w210, h0 * w200);
        float q1 = fmaf(h1, w211, h0 * w201);
        q0 = red16(q0);
        q1 = red16(q1);
        z1 += q0 + b20;   // DT = 1.0
        z2 += q1 + b21;
        if (g == 0) { float2 v; v.x = z1; v.y = z2; *(float2*)(zb + t * 2) = v; }
    }
}

// Kernel 2: streaming epilogue. Reads z (out2) + phi, writes a (out1) and xhat (out0).
// Each thread handles 2 adjacent t positions (float4 loads/stores).
__global__ __launch_bounds__(256) void finalize_kernel(
    const float* __restrict__ phi, const float* __restrict__ z,
    float* __restrict__ xhat, float* __restrict__ a)
{
    const int idx = blockIdx.x * blockDim.x + threadIdx.x;
    const int pos = idx * 2;                    // position pair (same b; t0 even)
    const int t0  = pos & (TT - 1);

    float4 zv = *(const float4*)(z   + (size_t)pos * 2);
    float4 pv = *(const float4*)(phi + (size_t)pos * 2);

    float k1a = tanh_fast(zv.x), k2a = tanh_fast(zv.y);
    float k1b = tanh_fast(zv.z), k2b = tanh_fast(zv.w);

    float a1a = k1a * (1.0f - k2a), a2a = k2a;
    float a1b = k1b * (1.0f - k2b), a2b = k2b;

    float4 av; av.x = a1a; av.y = a2a; av.z = a1b; av.w = a2b;
    *(float4*)(a + (size_t)pos * 2) = av;

    float x0 = (t0 >= 2)     ? fmaf(a2a, pv.y, a1a * pv.x) : 0.0f;
    float x1 = (t0 + 1 >= 2) ? fmaf(a2b, pv.w, a1b * pv.z) : 0.0f;
    float2 xv; xv.x = x0; xv.y = x1;
    *(float2*)(xhat + pos) = xv;
}

extern "C" void kernel_launch(void* const* d_in, const int* in_sizes, int n_in,
                              void* d_out, int out_size, void* d_ws, size_t ws_size,
                              hipStream_t stream) {
    const float* x    = (const float*)d_in[0];
    const float* phi  = (const float*)d_in[1];
    const float* ew1  = (const float*)d_in[2];
    const float* eb1  = (const float*)d_in[3];
    const float* ew2  = (const float*)d_in[4];
    const float* eb2  = (const float*)d_in[5];
    const float* fw1  = (const float*)d_in[6];
    const float* fb1  = (const float*)d_in[7];
    const float* fw2  = (const float*)d_in[8];
    const float* fb2  = (const float*)d_in[9];

    float* out  = (float*)d_out;
    float* xhat = out;                          // (B, T)       -> B*T floats
    float* a    = out + (size_t)BB * TT;        // (B, T, 2)    -> 2*B*T floats
    float* z    = out + (size_t)BB * TT * 3;    // (B, T, 2)    -> 2*B*T floats

    // 256 blocks x 64 threads: one wave per block, 4 chains per wave
    ode_scan_kernel<<<256, 64, 0, stream>>>(x, ew1, eb1, ew2, eb2,
                                            fw1, fb1, fw2, fb2, z);

    // (B*T/2) threads, 256/block
    const int total_pairs = (BB * TT) / 2;
    finalize_kernel<<<total_pairs / 256, 256, 0, stream>>>(phi, z, xhat, a);
}